// Round 2
// baseline (381.561 us; speedup 1.0000x reference)
//
#include <hip/hip_runtime.h>
#include <math.h>

// Problem constants (from reference)
#define NN 50000
#define NE 800000
#define NFEAT 128
#define NHID 64
#define NCLASS 16
#define NB_SCAN ((NN + 255) / 256)  // 196
#define GB ((NN + 63) / 64)         // 782 row-tiles for layer-1 GEMM

// fp32 <-> bf16 helpers (RNE round)
__device__ inline unsigned short f2bf(float f) {
    unsigned u = __builtin_bit_cast(unsigned, f);
    u += 0x7fffu + ((u >> 16) & 1u);
    return (unsigned short)(u >> 16);
}
__device__ inline float bf2f(unsigned short h) {
    return __builtin_bit_cast(float, (unsigned)h << 16);
}
// Packed edge: low 16 = col (NN < 65536), high 16 = weight as bf16.
__device__ inline float pk_w(unsigned v) { return bf2f((unsigned short)(v >> 16)); }
__device__ inline int pk_c(unsigned v) { return (int)(v & 0xffffu); }

// ---------------- CSR build ----------------

// Degree histogram only (rank assigned later by atomic cursor in scatter).
__global__ __launch_bounds__(256) void hist_kernel(const int* __restrict__ erow,
                                                   int* __restrict__ deg, int E) {
    int e = blockIdx.x * 256 + threadIdx.x;
    if (e < E) atomicAdd(&deg[erow[e]], 1);
}

__global__ __launch_bounds__(256) void scan_sum_kernel(const int* __restrict__ deg,
                                                       int* __restrict__ blocksum, int n) {
    __shared__ int s[256];
    const int t = threadIdx.x;
    int i = blockIdx.x * 256 + t;
    s[t] = (i < n) ? deg[i] : 0;
    __syncthreads();
#pragma unroll
    for (int off = 128; off > 0; off >>= 1) {
        if (t < off) s[t] += s[t + off];
        __syncthreads();
    }
    if (t == 0) blocksum[blockIdx.x] = s[0];
}

// Merged top-level + final scan; writes row_ptr AND a cursor copy for the atomic scatter.
__global__ __launch_bounds__(256) void scan_final_kernel(const int* __restrict__ deg,
                                                         const int* __restrict__ blocksum,
                                                         int* __restrict__ row_ptr,
                                                         int* __restrict__ cursor, int n) {
    __shared__ int bs[256];
    __shared__ int s[256];
    const int t = threadIdx.x;
    bs[t] = (t < NB_SCAN) ? blocksum[t] : 0;
    __syncthreads();
    for (int off = 1; off < 256; off <<= 1) {
        int u = (t >= off) ? bs[t - off] : 0;
        __syncthreads();
        bs[t] += u;
        __syncthreads();
    }
    const int blockpre = (blockIdx.x == 0) ? 0 : bs[blockIdx.x - 1];

    int i = blockIdx.x * 256 + t;
    int d = (i < n) ? deg[i] : 0;
    s[t] = d;
    __syncthreads();
    for (int off = 1; off < 256; off <<= 1) {
        int u = (t >= off) ? s[t - off] : 0;
        __syncthreads();
        s[t] += u;
        __syncthreads();
    }
    int excl = blockpre + s[t] - d;
    if (i < n) {
        row_ptr[i] = excl;
        cursor[i] = excl;
        if (i == n - 1) row_ptr[n] = excl + d;
    }
}

// Atomic-cursor scatter: single pass over edges, pos = atomicAdd(cursor[row],1).
// Replaces the 4x rr re-read scheme (saves ~16 MB traffic); edge order within a
// row becomes nondeterministic, which only perturbs fp add order.
__global__ __launch_bounds__(256) void scatter_atomic_kernel(const int* __restrict__ erow,
                                                             const int* __restrict__ ecol,
                                                             const float* __restrict__ ew,
                                                             int* __restrict__ cursor,
                                                             unsigned* __restrict__ pk, int E) {
    int e = blockIdx.x * 256 + threadIdx.x;
    if (e < E) {
        int r = erow[e];
        int pos = atomicAdd(&cursor[r], 1);
        pk[pos] = ((unsigned)f2bf(ew[e]) << 16) | (unsigned)ecol[e];
    }
}

// ---------------- Layer-1 GEMM: out[M,64] = in[M,128] @ W[128,64], bf16 out ----------------
template <int K, bool RELU_IN>
__global__ __launch_bounds__(256) void gemm64_kernel(const float* __restrict__ in,
                                                     const float* __restrict__ Wg,
                                                     unsigned short* __restrict__ outb, int M) {
    constexpr int KC = 64;
    __shared__ float xs[KC][68];
    __shared__ float Ws[KC][64];
    const int t = threadIdx.x;
    const int tx = t % 16;
    const int ty = t / 16;
    const int r0 = blockIdx.x * 64;

    float acc[4][4];
#pragma unroll
    for (int i = 0; i < 4; i++)
#pragma unroll
        for (int j = 0; j < 4; j++) acc[i][j] = 0.f;

    for (int k0 = 0; k0 < K; k0 += KC) {
        for (int i = t * 4; i < KC * 64; i += 1024) {
            *(float4*)&Ws[i / 64][i % 64] = *(const float4*)&Wg[(size_t)k0 * 64 + i];
        }
        {
            const int r = t / 4;
            const int q = t % 4;
            const int gr = r0 + r;
#pragma unroll
            for (int i = 0; i < 4; i++) {
                int k = q * 16 + i * 4;
                float4 v;
                if (gr < M)
                    v = *(const float4*)&in[(size_t)gr * K + k0 + k];
                else
                    v = make_float4(0.f, 0.f, 0.f, 0.f);
                if (RELU_IN) {
                    v.x = fmaxf(v.x, 0.f);
                    v.y = fmaxf(v.y, 0.f);
                    v.z = fmaxf(v.z, 0.f);
                    v.w = fmaxf(v.w, 0.f);
                }
                xs[k + 0][r] = v.x;
                xs[k + 1][r] = v.y;
                xs[k + 2][r] = v.z;
                xs[k + 3][r] = v.w;
            }
        }
        __syncthreads();
#pragma unroll 8
        for (int k = 0; k < KC; k++) {
            float4 xv = *(const float4*)&xs[k][ty * 4];
            float4 wv = *(const float4*)&Ws[k][tx * 4];
            acc[0][0] += xv.x * wv.x; acc[0][1] += xv.x * wv.y;
            acc[0][2] += xv.x * wv.z; acc[0][3] += xv.x * wv.w;
            acc[1][0] += xv.y * wv.x; acc[1][1] += xv.y * wv.y;
            acc[1][2] += xv.y * wv.z; acc[1][3] += xv.y * wv.w;
            acc[2][0] += xv.z * wv.x; acc[2][1] += xv.z * wv.y;
            acc[2][2] += xv.z * wv.z; acc[2][3] += xv.z * wv.w;
            acc[3][0] += xv.w * wv.x; acc[3][1] += xv.w * wv.y;
            acc[3][2] += xv.w * wv.z; acc[3][3] += xv.w * wv.w;
        }
        __syncthreads();
    }
#pragma unroll
    for (int i = 0; i < 4; i++) {
        int r = r0 + ty * 4 + i;
        if (r < M) {
            ushort4 u;
            u.x = f2bf(acc[i][0]);
            u.y = f2bf(acc[i][1]);
            u.z = f2bf(acc[i][2]);
            u.w = f2bf(acc[i][3]);
            *(ushort4*)&outb[(size_t)r * 64 + tx * 4] = u;
        }
    }
}

// ---------------- Fused SpMM(F=64) + next-layer dense GEMM ----------------
// One row per wave64 (F=64 == wave width): edge words are wave-uniform ->
// compiler scalarizes them (s_load, SALU weight unpack), gathers are 1 ushort
// per lane = one 128B line per edge, zero exec-mask divergence.
// Epilogue: block's 8 rows -> LDS, relu, 8x64 @ W(64xNOUT) -> bf16 nxt buffer.
// NOUT=64 for layers feeding W2/W3/W4, NOUT=16 for layer-4 feeding W5.
template <int NOUT>
__global__ __launch_bounds__(512) void spmm64_fused_kernel(
    const unsigned short* __restrict__ gb,   // gather source [*,64] bf16
    const int* __restrict__ row_ptr,
    const unsigned* __restrict__ pk,
    const float* __restrict__ bias,
    const float* __restrict__ Wn,            // [64, NOUT] fp32 (next layer)
    float* __restrict__ e_out,               // [M,64] fp32 (required output)
    unsigned short* __restrict__ nxt,        // [M,NOUT] bf16 (next layer input)
    int M) {
    __shared__ float Wlt[NOUT][65];          // transposed: Wlt[j][k]; 65-pad -> 2-way (free)
    __shared__ float xs[8][64];
    const int t = threadIdx.x;

    // Cooperative W stage (transposed). Coalesced global read.
    for (int idx = t; idx < 64 * NOUT; idx += 512) {
        int k = idx / NOUT, j = idx % NOUT;
        Wlt[j][k] = Wn[idx];
    }

    const int wv = __builtin_amdgcn_readfirstlane(t >> 6);  // wave id 0..7 (uniform)
    const int lane = t & 63;
    int r = blockIdx.x * 8 + wv;
    if (r >= M) r = M - 1;  // defensive; grid sized exactly (50000/8)

    float a = 0.f;
    int e = row_ptr[r];
    const int end = row_ptr[r + 1];
    for (; e + 8 <= end; e += 8) {
        unsigned q0 = pk[e + 0], q1 = pk[e + 1], q2 = pk[e + 2], q3 = pk[e + 3];
        unsigned q4 = pk[e + 4], q5 = pk[e + 5], q6 = pk[e + 6], q7 = pk[e + 7];
        a += pk_w(q0) * bf2f(gb[(size_t)pk_c(q0) * 64 + lane]);
        a += pk_w(q1) * bf2f(gb[(size_t)pk_c(q1) * 64 + lane]);
        a += pk_w(q2) * bf2f(gb[(size_t)pk_c(q2) * 64 + lane]);
        a += pk_w(q3) * bf2f(gb[(size_t)pk_c(q3) * 64 + lane]);
        a += pk_w(q4) * bf2f(gb[(size_t)pk_c(q4) * 64 + lane]);
        a += pk_w(q5) * bf2f(gb[(size_t)pk_c(q5) * 64 + lane]);
        a += pk_w(q6) * bf2f(gb[(size_t)pk_c(q6) * 64 + lane]);
        a += pk_w(q7) * bf2f(gb[(size_t)pk_c(q7) * 64 + lane]);
    }
    for (; e < end; ++e) {
        unsigned q = pk[e];
        a += pk_w(q) * bf2f(gb[(size_t)pk_c(q) * 64 + lane]);
    }
    float v = a + bias[lane];
    e_out[(size_t)r * 64 + lane] = v;
    xs[wv][lane] = fmaxf(v, 0.f);
    __syncthreads();

    // Epilogue GEMM: nxt[r][j] = sum_k relu(e[r][k]) * W[k][j]
    if (NOUT == 64) {
        const int rr = t >> 6;   // wave-uniform -> xs reads broadcast (free)
        const int j = t & 63;
        float acc = 0.f;
#pragma unroll 16
        for (int k = 0; k < 64; k++) acc += xs[rr][k] * Wlt[j][k];
        int gr = blockIdx.x * 8 + rr;
        if (gr < M) nxt[(size_t)gr * 64 + j] = f2bf(acc);
    } else {
        if (t < 8 * NOUT) {
            const int rr = t / NOUT;
            const int j = t % NOUT;
            float acc = 0.f;
#pragma unroll 16
            for (int k = 0; k < 64; k++) acc += xs[rr][k] * Wlt[j][k];
            int gr = blockIdx.x * 8 + rr;
            if (gr < M) nxt[(size_t)gr * NOUT + j] = f2bf(acc);
        }
    }
}

// ---------------- SpMM (F=16) fused with log_softmax ----------------
// One row per wave64: lane = 16*slot + f, 4 edge slots in parallel, shfl-reduce
// across slots. No divergent edge loops.
__global__ __launch_bounds__(256) void spmm16_lsm_kernel(const unsigned short* __restrict__ tmpc,
                                                         const int* __restrict__ row_ptr,
                                                         const unsigned* __restrict__ pk,
                                                         const float* __restrict__ bias,
                                                         float* __restrict__ e5,
                                                         float* __restrict__ out0, int M) {
    const int t = threadIdx.x;
    const int wv = __builtin_amdgcn_readfirstlane(t >> 6);  // wave 0..3
    const int lane = t & 63;
    const int f = lane & 15;
    const int s = lane >> 4;  // slot 0..3
    const int r = blockIdx.x * 4 + wv;
    if (r >= M) return;

    int e = row_ptr[r];
    const int end = row_ptr[r + 1];
    float acc = 0.f;
    for (; e + 8 <= end; e += 8) {
        unsigned qa = pk[e + s];
        unsigned qb = pk[e + 4 + s];
        acc += pk_w(qa) * bf2f(tmpc[(size_t)pk_c(qa) * 16 + f]);
        acc += pk_w(qb) * bf2f(tmpc[(size_t)pk_c(qb) * 16 + f]);
    }
    if (e + 4 <= end) {
        unsigned q = pk[e + s];
        acc += pk_w(q) * bf2f(tmpc[(size_t)pk_c(q) * 16 + f]);
        e += 4;
    }
    if (s < end - e) {
        unsigned q = pk[e + s];
        acc += pk_w(q) * bf2f(tmpc[(size_t)pk_c(q) * 16 + f]);
    }
    // reduce the 4 slots
    acc += __shfl_xor(acc, 16);
    acc += __shfl_xor(acc, 32);
    float v = acc + bias[f];

    // log-softmax over the 16 classes (within 16-lane groups; all slots redundant)
    float m = v;
#pragma unroll
    for (int off = 1; off < 16; off <<= 1) m = fmaxf(m, __shfl_xor(m, off, 16));
    float sum = expf(v - m);
#pragma unroll
    for (int off = 1; off < 16; off <<= 1) sum += __shfl_xor(sum, off, 16);
    float ls = logf(sum);
    if (lane < 16) {
        e5[(size_t)r * 16 + f] = v;
        out0[(size_t)r * 16 + f] = v - m - ls;
    }
}

// ---------------- launch ----------------

extern "C" void kernel_launch(void* const* d_in, const int* in_sizes, int n_in,
                              void* d_out, int out_size, void* d_ws, size_t ws_size,
                              hipStream_t stream) {
    const float* x = (const float*)d_in[0];
    const int* erow = (const int*)d_in[1];
    const int* ecol = (const int*)d_in[2];
    const float* ew = (const float*)d_in[3];
    const float* W1 = (const float*)d_in[4];
    const float* b1 = (const float*)d_in[5];
    const float* W2 = (const float*)d_in[6];
    const float* b2 = (const float*)d_in[7];
    const float* W3 = (const float*)d_in[8];
    const float* b3 = (const float*)d_in[9];
    const float* W4 = (const float*)d_in[10];
    const float* b4 = (const float*)d_in[11];
    const float* W5 = (const float*)d_in[12];
    const float* b5 = (const float*)d_in[13];

    // Output layout: log_softmax(e5), e1, e2, e3, e4, e5
    float* out0 = (float*)d_out;
    float* e1 = out0 + (size_t)NN * NCLASS;
    float* e2 = e1 + (size_t)NN * NHID;
    float* e3 = e2 + (size_t)NN * NHID;
    float* e4 = e3 + (size_t)NN * NHID;
    float* e5 = e4 + (size_t)NN * NHID;

    // Workspace layout
    char* ws = (char*)d_ws;
    unsigned short* tmpA = (unsigned short*)ws; ws += (size_t)NN * NHID * 2;   // 6.4 MB
    unsigned short* tmpB = (unsigned short*)ws; ws += (size_t)NN * NHID * 2;   // 6.4 MB
    unsigned short* tmpc = (unsigned short*)ws; ws += ((size_t)NN * NCLASS * 2 + 255) / 256 * 256;  // 1.6 MB
    int* deg = (int*)ws;      ws += ((size_t)NN * 4 + 255) / 256 * 256;        // zeroed below
    int* row_ptr = (int*)ws;  ws += ((size_t)(NN + 1) * 4 + 255) / 256 * 256;
    int* cursor = (int*)ws;   ws += ((size_t)NN * 4 + 255) / 256 * 256;
    int* blocksum = (int*)ws; ws += ((size_t)NB_SCAN * 4 + 255) / 256 * 256;
    unsigned* pk = (unsigned*)ws; ws += (size_t)NE * 4;                        // 3.2 MB packed edges

    // ---- CSR build: hist, scans, atomic-cursor scatter (no rank buffer) ----
    hipMemsetAsync(deg, 0, (size_t)NN * 4, stream);
    hist_kernel<<<(NE + 255) / 256, 256, 0, stream>>>(erow, deg, NE);
    scan_sum_kernel<<<NB_SCAN, 256, 0, stream>>>(deg, blocksum, NN);
    scan_final_kernel<<<NB_SCAN, 256, 0, stream>>>(deg, blocksum, row_ptr, cursor, NN);
    scatter_atomic_kernel<<<(NE + 255) / 256, 256, 0, stream>>>(erow, ecol, ew, cursor, pk, NE);

    // ---- Layer 1 dense: tmpA = x @ W1 (bf16) ----
    gemm64_kernel<NFEAT, false><<<GB, 256, 0, stream>>>(x, W1, tmpA, NN);

    // ---- Layers 1-4: fused SpMM + next dense GEMM ----
    const int FG = NN / 8;  // 6250 blocks x 8 rows
    spmm64_fused_kernel<64><<<FG, 512, 0, stream>>>(tmpA, row_ptr, pk, b1, W2, e1, tmpB, NN);
    spmm64_fused_kernel<64><<<FG, 512, 0, stream>>>(tmpB, row_ptr, pk, b2, W3, e2, tmpA, NN);
    spmm64_fused_kernel<64><<<FG, 512, 0, stream>>>(tmpA, row_ptr, pk, b3, W4, e3, tmpB, NN);
    spmm64_fused_kernel<16><<<FG, 512, 0, stream>>>(tmpB, row_ptr, pk, b4, W5, e4, tmpc, NN);

    // ---- Layer 5: SpMM(F=16) fused with log_softmax ----
    spmm16_lsm_kernel<<<(NN + 3) / 4, 256, 0, stream>>>(tmpc, row_ptr, pk, b5, e5, out0, NN);
}